// Round 5
// baseline (492.258 us; speedup 1.0000x reference)
//
#include <hip/hip_runtime.h>
#include <hip/hip_bf16.h>
#include <hip/hip_cooperative_groups.h>

namespace cg = cooperative_groups;

#define NN 10000
#define INDIM 128
#define HID 64
#define NB 256   // cooperative grid: 1 block/CU -> co-residency guaranteed

typedef __attribute__((ext_vector_type(8))) short bf16x8;
typedef __attribute__((ext_vector_type(4))) float f32x4;

// ==================== fallback path (proven R3 kernels) ====================
__global__ void k_zero(int* __restrict__ cnt) {
  int i = blockIdx.x * 256 + threadIdx.x;
  if (i < NN) cnt[i] = 0;
}

__global__ void k_count(const int* __restrict__ dst, int E, int* __restrict__ cnt) {
  int e = blockIdx.x * 256 + threadIdx.x;
  if (e < E) atomicAdd(&cnt[dst[e]], 1);
}

__global__ __launch_bounds__(1024) void k_scan(const int* __restrict__ cnt, int E,
                                               int* __restrict__ off, int* __restrict__ cursor,
                                               float* __restrict__ dis) {
  __shared__ int wsum[16];
  int t = threadIdx.x, lane = t & 63, wid = t >> 6;
  const int CH = (NN + 1023) / 1024;  // 10
  int base = t * CH;
  int s = 0;
  #pragma unroll
  for (int i = 0; i < CH; i++) { int idx = base + i; if (idx < NN) s += cnt[idx]; }
  int xs = s;
  #pragma unroll
  for (int d = 1; d < 64; d <<= 1) {
    int v = __shfl_up(xs, d, 64);
    if (lane >= d) xs += v;
  }
  if (lane == 63) wsum[wid] = xs;
  __syncthreads();
  if (wid == 0) {
    int w = (lane < 16) ? wsum[lane] : 0;
    #pragma unroll
    for (int d = 1; d < 16; d <<= 1) {
      int v = __shfl_up(w, d, 64);
      if (lane >= d) w += v;
    }
    if (lane < 16) wsum[lane] = w;
  }
  __syncthreads();
  int run = ((wid > 0) ? wsum[wid - 1] : 0) + (xs - s);
  #pragma unroll
  for (int i = 0; i < CH; i++) {
    int idx = base + i;
    if (idx < NN) {
      off[idx] = run;
      cursor[idx] = run;
      int c = cnt[idx];
      dis[idx] = rsqrtf((float)(c + 1));
      run += c;
    }
  }
  if (t == 0) off[NN] = E;
}

__global__ void k_scatter(const int* __restrict__ src, const int* __restrict__ dst, int E,
                          int* __restrict__ cursor, int* __restrict__ csr) {
  int e = blockIdx.x * 256 + threadIdx.x;
  if (e < E) {
    int p = atomicAdd(&cursor[dst[e]], 1);
    csr[p] = src[e];
  }
}

template <int K>
__global__ __launch_bounds__(256) void k_gemm(const float* __restrict__ x,
                                              const float* __restrict__ W,
                                              const float* __restrict__ dis,
                                              float* __restrict__ xws) {
  __shared__ float w[K * HID];
  int t = threadIdx.x;
  for (int i = t; i < K * HID; i += 256) w[i] = W[i];
  __syncthreads();
  int r = blockIdx.x * 4 + (t >> 6);
  int j = t & 63;
  float2 xv = ((const float2*)(x + (size_t)r * K))[j & (K / 2 - 1)];
  float acc = 0.f;
  #pragma unroll
  for (int k = 0; k < K; k++) {
    float xk = __shfl((k & 1) ? xv.y : xv.x, k >> 1, 64);
    acc = fmaf(xk, w[k * HID + j], acc);
  }
  xws[(size_t)r * HID + j] = acc * dis[r];
}

template <bool RELU, bool BF16OUT>
__global__ __launch_bounds__(256) void k_agg(const float* __restrict__ xws,
                                             const int* __restrict__ off,
                                             const int* __restrict__ csr,
                                             const float* __restrict__ dis,
                                             const float* __restrict__ b,
                                             void* __restrict__ hout) {
  int wid = threadIdx.x >> 6, lane = threadIdx.x & 63;
  int d = blockIdx.x * 4 + wid;
  int s0 = off[d], s1 = off[d + 1];
  float acc = xws[(size_t)d * HID + lane];
  int k = s0;
  for (; k + 4 <= s1; k += 4) {
    int i0 = csr[k], i1 = csr[k + 1], i2 = csr[k + 2], i3 = csr[k + 3];
    float v0 = xws[(size_t)i0 * HID + lane];
    float v1 = xws[(size_t)i1 * HID + lane];
    float v2 = xws[(size_t)i2 * HID + lane];
    float v3 = xws[(size_t)i3 * HID + lane];
    acc += v0 + v1 + v2 + v3;
  }
  for (; k < s1; k++) acc += xws[(size_t)csr[k] * HID + lane];
  float v = acc * dis[d] + b[lane];
  if (RELU) v = fmaxf(v, 0.f);
  if (BF16OUT)
    ((__hip_bfloat16*)hout)[(size_t)d * HID + lane] = __float2bfloat16(v);
  else
    ((float*)hout)[(size_t)d * HID + lane] = v;
}

// ==================== fused cooperative pre-pipeline ====================
__global__ __launch_bounds__(256, 2) void k_pre(
    const float* __restrict__ x, const int* __restrict__ ei, int E,
    const float* __restrict__ W1, const float* __restrict__ b1,
    const float* __restrict__ W2, const float* __restrict__ b2,
    int* __restrict__ cnt, int* __restrict__ off, int* __restrict__ cursor,
    float* __restrict__ dis, int* __restrict__ csr,
    float* __restrict__ xwA, float* __restrict__ hB,
    __hip_bfloat16* __restrict__ h2b) {
  cg::grid_group grid = cg::this_grid();
  __shared__ float smem[INDIM * HID];  // 32 KB: W staging
  __shared__ int wsum[4];

  const int t = threadIdx.x, b = blockIdx.x;
  const int lane = t & 63, wid = t >> 6;
  const int tid = b * 256 + t;
  const int nthr = gridDim.x * 256;
  const int* src = ei;
  const int* dst = ei + E;

  // P0: zero counts
  for (int i = tid; i < NN; i += nthr) cnt[i] = 0;
  grid.sync();

  // P1: count in-degree
  for (int e = tid; e < E; e += nthr) atomicAdd(&cnt[dst[e]], 1);
  grid.sync();

  // P2: exclusive scan (block 0) -> off/cursor, dis = (deg+1)^-1/2
  if (b == 0) {
    const int CH = (NN + 255) / 256;  // 40
    int base = t * CH;
    int s = 0;
    for (int i = 0; i < CH; i++) {
      int idx = base + i;
      if (idx < NN) s += cnt[idx];
    }
    int xs = s;
    #pragma unroll
    for (int d = 1; d < 64; d <<= 1) {
      int v = __shfl_up(xs, d, 64);
      if (lane >= d) xs += v;
    }
    if (lane == 63) wsum[wid] = xs;
    __syncthreads();
    int pre = 0;
    for (int w = 0; w < wid; w++) pre += wsum[w];
    int run = pre + (xs - s);
    for (int i = 0; i < CH; i++) {
      int idx = base + i;
      if (idx < NN) {
        int c = cnt[idx];
        off[idx] = run;
        cursor[idx] = run;
        dis[idx] = rsqrtf((float)(c + 1));
        run += c;
      }
    }
    if (t == 0) off[NN] = E;
  }
  grid.sync();

  // P3: scatter edges into CSR
  for (int e = tid; e < E; e += nthr) {
    int p = atomicAdd(&cursor[dst[e]], 1);
    csr[p] = src[e];
  }
  grid.sync();

  // P4: xwA[r] = dis[r] * (x[r] @ W1)
  for (int i = t; i < INDIM * HID; i += 256) smem[i] = W1[i];
  __syncthreads();
  for (int r = b * 4 + wid; r < NN; r += gridDim.x * 4) {
    float2 xv = ((const float2*)(x + (size_t)r * INDIM))[lane & (INDIM / 2 - 1)];
    float acc = 0.f;
    #pragma unroll
    for (int k = 0; k < INDIM; k++) {
      float xk = __shfl((k & 1) ? xv.y : xv.x, k >> 1, 64);
      acc = fmaf(xk, smem[k * HID + lane], acc);
    }
    xwA[(size_t)r * HID + lane] = acc * dis[r];
  }
  grid.sync();

  // P5: hB = relu(dis * (self + gathered) + b1)
  for (int d = b * 4 + wid; d < NN; d += gridDim.x * 4) {
    int s0 = off[d], s1 = off[d + 1];
    float acc = xwA[(size_t)d * HID + lane];
    int k = s0;
    for (; k + 4 <= s1; k += 4) {
      int i0 = csr[k], i1 = csr[k + 1], i2 = csr[k + 2], i3 = csr[k + 3];
      float v0 = xwA[(size_t)i0 * HID + lane];
      float v1 = xwA[(size_t)i1 * HID + lane];
      float v2 = xwA[(size_t)i2 * HID + lane];
      float v3 = xwA[(size_t)i3 * HID + lane];
      acc += v0 + v1 + v2 + v3;
    }
    for (; k < s1; k++) acc += xwA[(size_t)csr[k] * HID + lane];
    float v = acc * dis[d] + b1[lane];
    hB[(size_t)d * HID + lane] = fmaxf(v, 0.f);
  }
  grid.sync();

  // P6: xwA[r] = dis[r] * (hB[r] @ W2)
  for (int i = t; i < HID * HID; i += 256) smem[i] = W2[i];
  __syncthreads();
  for (int r = b * 4 + wid; r < NN; r += gridDim.x * 4) {
    float2 xv = ((const float2*)(hB + (size_t)r * HID))[lane & (HID / 2 - 1)];
    float acc = 0.f;
    #pragma unroll
    for (int k = 0; k < HID; k++) {
      float xk = __shfl((k & 1) ? xv.y : xv.x, k >> 1, 64);
      acc = fmaf(xk, smem[k * HID + lane], acc);
    }
    xwA[(size_t)r * HID + lane] = acc * dis[r];
  }
  grid.sync();

  // P7: h2b = bf16(dis * (self + gathered) + b2)
  for (int d = b * 4 + wid; d < NN; d += gridDim.x * 4) {
    int s0 = off[d], s1 = off[d + 1];
    float acc = xwA[(size_t)d * HID + lane];
    int k = s0;
    for (; k + 4 <= s1; k += 4) {
      int i0 = csr[k], i1 = csr[k + 1], i2 = csr[k + 2], i3 = csr[k + 3];
      float v0 = xwA[(size_t)i0 * HID + lane];
      float v1 = xwA[(size_t)i1 * HID + lane];
      float v2 = xwA[(size_t)i2 * HID + lane];
      float v3 = xwA[(size_t)i3 * HID + lane];
      acc += v0 + v1 + v2 + v3;
    }
    for (; k < s1; k++) acc += xwA[(size_t)csr[k] * HID + lane];
    float v = acc * dis[d] + b2[lane];
    h2b[(size_t)d * HID + lane] = __float2bfloat16(v);
  }
}

// ==================== final: out = sigmoid(h2 @ h2^T) ====================
// One wave per 64x64 tile (4x4 accs of 16x16x32 MFMA, K=64). Z symmetric:
// 16x16 subtiles stored transposed -> contiguous float4/lane; ct outer,
// rt inner so each row's four 64B segments issue back-to-back (L2 merges
// full lines; cached stores -- nontemporal was the R2 bottleneck).
__global__ __launch_bounds__(256) void k_final(const short* __restrict__ hb,
                                               float* __restrict__ out) {
  const int T = (NN + 63) / 64;  // 157
  int wid = threadIdx.x >> 6, lane = threadIdx.x & 63;
  int tx = blockIdx.x * 2 + (wid & 1);
  int ty = blockIdx.y * 2 + (wid >> 1);
  if (tx >= T || ty >= T) return;
  int rowbase = tx * 64, colbase = ty * 64;
  int m = lane & 15, q = lane >> 4;

  bf16x8 a0[4], a1[4], b0[4], b1[4];
  #pragma unroll
  for (int rt = 0; rt < 4; rt++) {
    int r = rowbase + rt * 16 + m; r = r < NN ? r : NN - 1;
    const bf16x8* p = reinterpret_cast<const bf16x8*>(hb + (size_t)r * HID + q * 8);
    a0[rt] = p[0]; a1[rt] = p[4];
  }
  #pragma unroll
  for (int ct = 0; ct < 4; ct++) {
    int r = colbase + ct * 16 + m; r = r < NN ? r : NN - 1;
    const bf16x8* p = reinterpret_cast<const bf16x8*>(hb + (size_t)r * HID + q * 8);
    b0[ct] = p[0]; b1[ct] = p[4];
  }

  f32x4 acc[4][4];
  #pragma unroll
  for (int rt = 0; rt < 4; rt++)
    #pragma unroll
    for (int ct = 0; ct < 4; ct++) {
      f32x4 z = {0.f, 0.f, 0.f, 0.f};
      z = __builtin_amdgcn_mfma_f32_16x16x32_bf16(a0[rt], b0[ct], z, 0, 0, 0);
      z = __builtin_amdgcn_mfma_f32_16x16x32_bf16(a1[rt], b1[ct], z, 0, 0, 0);
      acc[rt][ct] = z;
    }

  #pragma unroll
  for (int ct = 0; ct < 4; ct++)
    #pragma unroll
    for (int rt = 0; rt < 4; rt++) {
      if (rowbase + rt * 16 < NN && colbase + ct * 16 < NN) {  // wave-uniform
        f32x4 z = acc[rt][ct], o;
        #pragma unroll
        for (int r = 0; r < 4; r++)
          o[r] = __builtin_amdgcn_rcpf(1.0f + __expf(-z[r]));
        size_t orow = (size_t)(colbase + ct * 16 + m);
        size_t ocol = (size_t)(rowbase + rt * 16 + q * 4);
        *reinterpret_cast<f32x4*>(out + orow * NN + ocol) = o;
      }
    }
}

extern "C" void kernel_launch(void* const* d_in, const int* in_sizes, int n_in,
                              void* d_out, int out_size, void* d_ws, size_t ws_size,
                              hipStream_t stream) {
  const float* x  = (const float*)d_in[0];
  const int*   ei = (const int*)d_in[1];
  const float* W1 = (const float*)d_in[2];
  const float* b1 = (const float*)d_in[3];
  const float* W2 = (const float*)d_in[4];
  const float* b2 = (const float*)d_in[5];
  int E = in_sizes[1] / 2;
  const int* src = ei;
  const int* dst = ei + E;

  // Scratch inside d_out (dead before k_final rewrites it); h2b in d_ws.
  char* base = (char*)d_out;
  float* xwA  = (float*)(base);                          // 640000 f32
  float* hB   = (float*)(base + 2560000);                // 640000 f32
  int*   csr  = (int*)(base + 5120000);                  // E ints
  char*  p2   = base + 5120000 + 4 * (size_t)E;
  int*   cnt    = (int*)(p2);
  int*   off    = (int*)(p2 + 40064);
  int*   cursor = (int*)(p2 + 80128);
  float* dis    = (float*)(p2 + 120192);
  __hip_bfloat16* h2b = (__hip_bfloat16*)d_ws;           // 1.28 MB

  void* args[] = {(void*)&x, (void*)&ei, (void*)&E, (void*)&W1, (void*)&b1,
                  (void*)&W2, (void*)&b2, (void*)&cnt, (void*)&off, (void*)&cursor,
                  (void*)&dis, (void*)&csr, (void*)&xwA, (void*)&hB, (void*)&h2b};
  hipError_t cerr = hipLaunchCooperativeKernel((void*)k_pre, dim3(NB), dim3(256),
                                               args, 0, stream);
  if (cerr != hipSuccess) {
    // Fallback: proven R3 multi-kernel path (identical math).
    k_zero<<<(NN + 255) / 256, 256, 0, stream>>>(cnt);
    k_count<<<(E + 255) / 256, 256, 0, stream>>>(dst, E, cnt);
    k_scan<<<1, 1024, 0, stream>>>(cnt, E, off, cursor, dis);
    k_scatter<<<(E + 255) / 256, 256, 0, stream>>>(src, dst, E, cursor, csr);
    k_gemm<INDIM><<<NN / 4, 256, 0, stream>>>(x, W1, dis, xwA);
    k_agg<true, false><<<NN / 4, 256, 0, stream>>>(xwA, off, csr, dis, b1, hB);
    k_gemm<HID><<<NN / 4, 256, 0, stream>>>(hB, W2, dis, xwA);
    k_agg<false, true><<<NN / 4, 256, 0, stream>>>(xwA, off, csr, dis, b2, h2b);
  }

  const int T = (NN + 63) / 64;           // 157
  dim3 gf((T + 1) / 2, (T + 1) / 2);      // 79 x 79, 2x2 waves of 64x64 each
  k_final<<<gf, 256, 0, stream>>>((const short*)h2b, (float*)d_out);
}

// Round 6
// 201.131 us; speedup vs baseline: 2.4474x; 2.4474x over previous
//
#include <hip/hip_runtime.h>
#include <hip/hip_bf16.h>

#define NN 10000
#define INDIM 128
#define HID 64
#define CB 1250   // count blocks   (E/256)
#define GB 2500   // gemm1 blocks   (NN/4)
#define SB 1250   // scatter blocks (E/256)
#define PB 313    // prescale blocks ceil(NN*HID/(256*8))

typedef __attribute__((ext_vector_type(8))) short bf16x8;
typedef __attribute__((ext_vector_type(4))) float f32x4;

// ---- node 2: in-degree count  ∪  gemm1 (unscaled x@W1) ----
// gemm1 deliberately does NOT apply dis (so it needn't wait for the scan);
// the scale rides with the scatter node instead. This lets count and gemm1
// share one kernel node: disjoint block ranges, no interaction.
__global__ __launch_bounds__(256) void k_count_gemm1(
    const int* __restrict__ dst, int E, int* __restrict__ cnt,
    const float* __restrict__ x, const float* __restrict__ W1,
    float* __restrict__ xw) {
  __shared__ float w[INDIM * HID];  // 32 KB (allocated by count blocks too; occ 5/CU fine)
  int b = blockIdx.x, t = threadIdx.x;
  if (b < CB) {
    int e = b * 256 + t;
    if (e < E) atomicAdd(&cnt[dst[e]], 1);
  } else {
    for (int i = t; i < INDIM * HID; i += 256) w[i] = W1[i];
    __syncthreads();
    int r = (b - CB) * 4 + (t >> 6);
    int j = t & 63;
    float2 xv = ((const float2*)(x + (size_t)r * INDIM))[j & (INDIM / 2 - 1)];
    float acc = 0.f;
    #pragma unroll
    for (int k = 0; k < INDIM; k++) {
      float xk = __shfl((k & 1) ? xv.y : xv.x, k >> 1, 64);
      acc = fmaf(xk, w[k * HID + j], acc);
    }
    xw[(size_t)r * HID + j] = acc;   // unscaled
  }
}

// ---- node 3: single-block scan (proven R3 kernel) ----
__global__ __launch_bounds__(1024) void k_scan(const int* __restrict__ cnt, int E,
                                               int* __restrict__ off, int* __restrict__ cursor,
                                               float* __restrict__ dis) {
  __shared__ int wsum[16];
  int t = threadIdx.x, lane = t & 63, wid = t >> 6;
  const int CH = (NN + 1023) / 1024;  // 10
  int base = t * CH;
  int s = 0;
  #pragma unroll
  for (int i = 0; i < CH; i++) { int idx = base + i; if (idx < NN) s += cnt[idx]; }
  int xs = s;
  #pragma unroll
  for (int d = 1; d < 64; d <<= 1) {
    int v = __shfl_up(xs, d, 64);
    if (lane >= d) xs += v;
  }
  if (lane == 63) wsum[wid] = xs;
  __syncthreads();
  if (wid == 0) {
    int w = (lane < 16) ? wsum[lane] : 0;
    #pragma unroll
    for (int d = 1; d < 16; d <<= 1) {
      int v = __shfl_up(w, d, 64);
      if (lane >= d) w += v;
    }
    if (lane < 16) wsum[lane] = w;
  }
  __syncthreads();
  int run = ((wid > 0) ? wsum[wid - 1] : 0) + (xs - s);
  #pragma unroll
  for (int i = 0; i < CH; i++) {
    int idx = base + i;
    if (idx < NN) {
      off[idx] = run;
      cursor[idx] = run;
      int c = cnt[idx];
      dis[idx] = rsqrtf((float)(c + 1));
      run += c;
    }
  }
  if (t == 0) off[NN] = E;
}

// ---- node 4: CSR scatter  ∪  prescale xw *= dis[row] ----
__global__ __launch_bounds__(256) void k_scatter_scale(
    const int* __restrict__ src, const int* __restrict__ dst, int E,
    int* __restrict__ cursor, int* __restrict__ csr,
    const float* __restrict__ dis, float* __restrict__ xw) {
  int b = blockIdx.x, t = threadIdx.x;
  if (b < SB) {
    int e = b * 256 + t;
    if (e < E) {
      int p = atomicAdd(&cursor[dst[e]], 1);
      csr[p] = src[e];
    }
  } else {
    size_t i8 = ((size_t)(b - SB) * 256 + t) * 8;   // 8 elems, all in one 64-wide row
    if (i8 < (size_t)NN * HID) {
      float ds = dis[i8 >> 6];
      float4* p0 = (float4*)(xw + i8);
      float4 v0 = p0[0], v1 = p0[1];
      v0.x *= ds; v0.y *= ds; v0.z *= ds; v0.w *= ds;
      v1.x *= ds; v1.y *= ds; v1.z *= ds; v1.w *= ds;
      p0[0] = v0; p0[1] = v1;
    }
  }
}

// ---- node 5: agg1 + bias + relu + gemm2 + dis-scale, fused ----
// The aggregated row lives in registers (lane j = dim j), so the row-local
// matvec h@W2 runs immediately via shfl broadcast -- no hB round-trip.
__global__ __launch_bounds__(256) void k_agg1_gemm2(
    const float* __restrict__ xw, const int* __restrict__ off,
    const int* __restrict__ csr, const float* __restrict__ dis,
    const float* __restrict__ b1, const float* __restrict__ W2,
    float* __restrict__ hB) {
  __shared__ float w[HID * HID];  // 16 KB
  int t = threadIdx.x;
  for (int i = t; i < HID * HID; i += 256) w[i] = W2[i];
  __syncthreads();
  int wid = t >> 6, lane = t & 63;
  int d = blockIdx.x * 4 + wid;
  int s0 = off[d], s1 = off[d + 1];
  float acc = xw[(size_t)d * HID + lane];   // self-loop
  int k = s0;
  for (; k + 8 <= s1; k += 8) {             // 8-deep: latency tolerance
    int i0 = csr[k],     i1 = csr[k + 1], i2 = csr[k + 2], i3 = csr[k + 3];
    int i4 = csr[k + 4], i5 = csr[k + 5], i6 = csr[k + 6], i7 = csr[k + 7];
    float v0 = xw[(size_t)i0 * HID + lane], v1 = xw[(size_t)i1 * HID + lane];
    float v2 = xw[(size_t)i2 * HID + lane], v3 = xw[(size_t)i3 * HID + lane];
    float v4 = xw[(size_t)i4 * HID + lane], v5 = xw[(size_t)i5 * HID + lane];
    float v6 = xw[(size_t)i6 * HID + lane], v7 = xw[(size_t)i7 * HID + lane];
    acc += ((v0 + v1) + (v2 + v3)) + ((v4 + v5) + (v6 + v7));
  }
  for (; k < s1; k++) acc += xw[(size_t)csr[k] * HID + lane];
  float h = fmaxf(acc * dis[d] + b1[lane], 0.f);
  float acc2 = 0.f;
  #pragma unroll
  for (int kk = 0; kk < HID; kk++)
    acc2 = fmaf(__shfl(h, kk, 64), w[kk * HID + lane], acc2);
  hB[(size_t)d * HID + lane] = acc2 * dis[d];
}

// ---- node 6: agg2 + bias -> bf16 h2 ----
__global__ __launch_bounds__(256) void k_agg2(
    const float* __restrict__ hB, const int* __restrict__ off,
    const int* __restrict__ csr, const float* __restrict__ dis,
    const float* __restrict__ b2, __hip_bfloat16* __restrict__ h2b) {
  int t = threadIdx.x, wid = t >> 6, lane = t & 63;
  int d = blockIdx.x * 4 + wid;
  int s0 = off[d], s1 = off[d + 1];
  float acc = hB[(size_t)d * HID + lane];
  int k = s0;
  for (; k + 8 <= s1; k += 8) {
    int i0 = csr[k],     i1 = csr[k + 1], i2 = csr[k + 2], i3 = csr[k + 3];
    int i4 = csr[k + 4], i5 = csr[k + 5], i6 = csr[k + 6], i7 = csr[k + 7];
    float v0 = hB[(size_t)i0 * HID + lane], v1 = hB[(size_t)i1 * HID + lane];
    float v2 = hB[(size_t)i2 * HID + lane], v3 = hB[(size_t)i3 * HID + lane];
    float v4 = hB[(size_t)i4 * HID + lane], v5 = hB[(size_t)i5 * HID + lane];
    float v6 = hB[(size_t)i6 * HID + lane], v7 = hB[(size_t)i7 * HID + lane];
    acc += ((v0 + v1) + (v2 + v3)) + ((v4 + v5) + (v6 + v7));
  }
  for (; k < s1; k++) acc += hB[(size_t)csr[k] * HID + lane];
  float v = acc * dis[d] + b2[lane];
  h2b[(size_t)d * HID + lane] = __float2bfloat16(v);
}

// ---- node 7: out = sigmoid(h2 @ h2^T) ----
// One wave per 64x64 tile (4x4 accs of 16x16x32 MFMA, K=64). Z symmetric:
// 16x16 subtiles stored transposed -> contiguous float4/lane; ct outer,
// rt inner so each row's four 64B segments issue back-to-back (L2 merges
// full lines; cached stores -- nontemporal was the R2 bottleneck).
__global__ __launch_bounds__(256) void k_final(const short* __restrict__ hb,
                                               float* __restrict__ out) {
  const int T = (NN + 63) / 64;  // 157
  int wid = threadIdx.x >> 6, lane = threadIdx.x & 63;
  int tx = blockIdx.x * 2 + (wid & 1);
  int ty = blockIdx.y * 2 + (wid >> 1);
  if (tx >= T || ty >= T) return;
  int rowbase = tx * 64, colbase = ty * 64;
  int m = lane & 15, q = lane >> 4;

  bf16x8 a0[4], a1[4], b0[4], b1[4];
  #pragma unroll
  for (int rt = 0; rt < 4; rt++) {
    int r = rowbase + rt * 16 + m; r = r < NN ? r : NN - 1;
    const bf16x8* p = reinterpret_cast<const bf16x8*>(hb + (size_t)r * HID + q * 8);
    a0[rt] = p[0]; a1[rt] = p[4];
  }
  #pragma unroll
  for (int ct = 0; ct < 4; ct++) {
    int r = colbase + ct * 16 + m; r = r < NN ? r : NN - 1;
    const bf16x8* p = reinterpret_cast<const bf16x8*>(hb + (size_t)r * HID + q * 8);
    b0[ct] = p[0]; b1[ct] = p[4];
  }

  f32x4 acc[4][4];
  #pragma unroll
  for (int rt = 0; rt < 4; rt++)
    #pragma unroll
    for (int ct = 0; ct < 4; ct++) {
      f32x4 z = {0.f, 0.f, 0.f, 0.f};
      z = __builtin_amdgcn_mfma_f32_16x16x32_bf16(a0[rt], b0[ct], z, 0, 0, 0);
      z = __builtin_amdgcn_mfma_f32_16x16x32_bf16(a1[rt], b1[ct], z, 0, 0, 0);
      acc[rt][ct] = z;
    }

  #pragma unroll
  for (int ct = 0; ct < 4; ct++)
    #pragma unroll
    for (int rt = 0; rt < 4; rt++) {
      if (rowbase + rt * 16 < NN && colbase + ct * 16 < NN) {  // wave-uniform
        f32x4 z = acc[rt][ct], o;
        #pragma unroll
        for (int r = 0; r < 4; r++)
          o[r] = __builtin_amdgcn_rcpf(1.0f + __expf(-z[r]));
        size_t orow = (size_t)(colbase + ct * 16 + m);
        size_t ocol = (size_t)(rowbase + rt * 16 + q * 4);
        *reinterpret_cast<f32x4*>(out + orow * NN + ocol) = o;
      }
    }
}

extern "C" void kernel_launch(void* const* d_in, const int* in_sizes, int n_in,
                              void* d_out, int out_size, void* d_ws, size_t ws_size,
                              hipStream_t stream) {
  const float* x  = (const float*)d_in[0];
  const int*   ei = (const int*)d_in[1];
  const float* W1 = (const float*)d_in[2];
  const float* b1 = (const float*)d_in[3];
  const float* W2 = (const float*)d_in[4];
  const float* b2 = (const float*)d_in[5];
  int E = in_sizes[1] / 2;
  const int* src = ei;
  const int* dst = ei + E;

  // Scratch inside d_out (dead before k_final rewrites it); h2b in d_ws.
  char* base = (char*)d_out;
  float* xwA  = (float*)(base);                          // 640000 f32
  float* hB   = (float*)(base + 2560000);                // 640000 f32
  int*   csr  = (int*)(base + 5120000);                  // E ints
  char*  p2   = base + 5120000 + 4 * (size_t)E;
  int*   cnt    = (int*)(p2);
  int*   off    = (int*)(p2 + 40064);
  int*   cursor = (int*)(p2 + 80128);
  float* dis    = (float*)(p2 + 120192);
  __hip_bfloat16* h2b = (__hip_bfloat16*)d_ws;           // 1.28 MB

  hipMemsetAsync(cnt, 0, NN * sizeof(int), stream);                       // node 1
  k_count_gemm1<<<CB + GB, 256, 0, stream>>>(dst, E, cnt, x, W1, xwA);    // node 2
  k_scan<<<1, 1024, 0, stream>>>(cnt, E, off, cursor, dis);               // node 3
  k_scatter_scale<<<SB + PB, 256, 0, stream>>>(src, dst, E, cursor, csr,
                                               dis, xwA);                 // node 4
  k_agg1_gemm2<<<NN / 4, 256, 0, stream>>>(xwA, off, csr, dis, b1, W2, hB); // node 5
  k_agg2<<<NN / 4, 256, 0, stream>>>(hB, off, csr, dis, b2, h2b);         // node 6

  const int T = (NN + 63) / 64;           // 157
  dim3 gf((T + 1) / 2, (T + 1) / 2);      // 79 x 79, 2x2 waves of 64x64 each
  k_final<<<gf, 256, 0, stream>>>((const short*)h2b, (float*)d_out);      // node 7
}